// Round 12
// baseline (200.609 us; speedup 1.0000x reference)
//
#include <hip/hip_runtime.h>
#include <hip/hip_bf16.h>

#define B_    16
#define CIN_  128
#define COUT_ 256
#define H_    80
#define W_    80
#define HO_   40
#define WO_   40
#define KK_   9
#define SK_   1152      // CIN_*KK_
#define NPIX_ 25600     // B_*HO_*WO_
#define NKS_  36        // K / 32

typedef __attribute__((ext_vector_type(8))) short short8;
typedef __attribute__((ext_vector_type(4))) float floatx4;

__device__ __forceinline__ unsigned short f2bu(float v) {
  __hip_bfloat16 h = __float2bfloat16(v);
  return *reinterpret_cast<unsigned short*>(&h);
}
__device__ __forceinline__ float bu2f(unsigned short u) {
  return __uint_as_float(((unsigned)u) << 16);
}
__device__ __forceinline__ unsigned int pk2(float a, float b) {
  return (unsigned)f2bu(a) | ((unsigned)f2bu(b) << 16);
}
// async global->LDS DMA, 16B per lane. LDS dest = wave-uniform base + lane*16.
__device__ __forceinline__ void gl_lds16(const unsigned short* g, unsigned short* l) {
  __builtin_amdgcn_global_load_lds(
      (const __attribute__((address_space(1))) unsigned int*)(const void*)g,
      (__attribute__((address_space(3))) unsigned int*)(void*)l, 16, 0, 0);
}

// ------------------------------------------------- KT: pack weights for MFMA
// (verified round 3) K reordered as s' = kk*128 + ci. Apk[ks][m][quad][j] bf16.
// Block 0 also zeroes the stats accumulator (consumed 2 dispatches later).
__global__ __launch_bounds__(256) void k_pack(const float* __restrict__ dw,
                                              unsigned short* __restrict__ Apk,
                                              float* __restrict__ accum) {
  if (blockIdx.x == 0) {
    accum[threadIdx.x] = 0.f;
    accum[256 + threadIdx.x] = 0.f;
  }
  int t = blockIdx.x * 256 + threadIdx.x;   // 0..294911
  int j  = t & 7;
  int qd = (t >> 3) & 3;
  int m  = (t >> 5) & 255;
  int ks = t >> 13;
  int k  = ks * 32 + qd * 8 + j;
  int kk = k >> 7, ci = k & 127;
  Apk[t] = f2bu(dw[m * SK_ + ci * KK_ + kk]);
}

// --------------- KC v2: x -> channels-last bf16 + fused offset conv
// (verified round 11) XCD-affine, packed-bf16 LDS tile, conflict-free.
__global__ __launch_bounds__(256) void k_cl(const float* __restrict__ x,
                                            const float* __restrict__ ow,
                                            const float* __restrict__ ob,
                                            unsigned short* __restrict__ xcl,
                                            float* __restrict__ off) {
  __shared__ unsigned int ts[CIN_ * 41];   // 21 KB
  __shared__ float owl[18 * CIN_];         // 9.2 KB
  __shared__ float obl[18];
  const int tid = threadIdx.x;
  const int bid = blockIdx.x;              // 0..1279
  const int xcd = bid & 7;
  const int i0_ = bid >> 3;                // 0..159
  const int b   = (i0_ / 80) * 8 + xcd;
  const int y   = i0_ % 80;
  const bool even = (y & 1) == 0;

  for (int j = tid; j < CIN_ * 20; j += 256) {
    int ci = j / 20, xq = j % 20;
    float4 v = *(const float4*)&x[(((size_t)b * CIN_ + ci) * H_ + y) * W_ + xq * 4];
    ts[ci * 41 + xq * 2 + 0] = pk2(v.x, v.y);
    ts[ci * 41 + xq * 2 + 1] = pk2(v.z, v.w);
  }
  if (even) {
    for (int j = tid; j < 18 * CIN_; j += 256) owl[j] = ow[j];
    if (tid < 18) obl[tid] = ob[tid];
  }
  __syncthreads();

  unsigned short* op = xcl + ((size_t)b * H_ * W_ + (size_t)y * W_) * CIN_;
  for (int j = tid; j < 40 * 32; j += 256) {
    int xw = j >> 5, cg = j & 31;
    unsigned w0 = ts[(cg * 4 + 0) * 41 + xw];
    unsigned w1 = ts[(cg * 4 + 1) * 41 + xw];
    unsigned w2 = ts[(cg * 4 + 2) * 41 + xw];
    unsigned w3 = ts[(cg * 4 + 3) * 41 + xw];
    uint2 lo = make_uint2((w0 & 0xFFFFu) | (w1 << 16),
                          (w2 & 0xFFFFu) | (w3 << 16));
    uint2 hi = make_uint2((w0 >> 16) | (w1 & 0xFFFF0000u),
                          (w2 >> 16) | (w3 & 0xFFFF0000u));
    *(uint2*)(op + (size_t)(2 * xw) * CIN_ + cg * 4)     = lo;
    *(uint2*)(op + (size_t)(2 * xw + 1) * CIN_ + cg * 4) = hi;
  }

  if (even) {
    const int ho = y >> 1;
    for (int i = tid; i < 18 * WO_; i += 256) {
      int o = i / WO_, wo = i - o * WO_;
      float acc = obl[o];
      const float* wr = &owl[o * CIN_];
#pragma unroll 4
      for (int ci = 0; ci < CIN_; ci++)
        acc += wr[ci] * bu2f((unsigned short)(ts[ci * 41 + wo] & 0xFFFFu));
      off[((b * 18 + o) * HO_ + ho) * WO_ + wo] = acc;
    }
  }
}

// ------------------------------------------ K2a: sampling from channels-last
// (verified round 6) XCD-swizzled by b; coalesced 16B corner loads.
__global__ __launch_bounds__(256) void k_sample_cl(const unsigned short* __restrict__ xcl,
                                                   const float* __restrict__ off,
                                                   unsigned short* __restrict__ Spk) {
  __shared__ __align__(16) int   pidx[80 * 4];
  __shared__ __align__(16) float pw[80 * 4];
  const int tid = threadIdx.x;
  const int j0   = blockIdx.x;         // 0..2879
  const int xcd  = j0 & 7;
  const int s    = j0 >> 3;
  const int b_hi = s / 180;
  const int t0   = s % 180;
  const int g    = t0 / 9;
  const int kk   = t0 % 9;
  const int b    = b_hi * 8 + xcd;
  const int ho0  = g * 2;

  if (tid < 80) {
    int hop = tid / 40, px = tid % 40;
    int ho = ho0 + hop;
    float dy = off[((b * 18 + 2 * kk) * HO_ + ho) * WO_ + px];
    float dx = off[((b * 18 + 2 * kk + 1) * HO_ + ho) * WO_ + px];
    float py  = (float)(2 * ho - 1 + (kk / 3)) + dy;
    float pxf = (float)(2 * px - 1 + (kk % 3)) + dx;
    float y0f = floorf(py), x0f = floorf(pxf);
    float wy1 = py - y0f, wx1 = pxf - x0f;
    float wy0 = 1.f - wy1, wx0 = 1.f - wx1;
    int y0 = (int)y0f, x0 = (int)x0f;
    int y1 = y0 + 1, x1 = x0 + 1;
    bool vy0 = (y0 >= 0) && (y0 < H_);
    bool vy1 = (y1 >= 0) && (y1 < H_);
    bool vx0 = (x0 >= 0) && (x0 < W_);
    bool vx1 = (x1 >= 0) && (x1 < W_);
    int y0c = min(max(y0, 0), H_ - 1), y1c = min(max(y1, 0), H_ - 1);
    int x0c = min(max(x0, 0), W_ - 1), x1c = min(max(x1, 0), W_ - 1);
    pidx[tid * 4 + 0] = (y0c * W_ + x0c) << 7;  pw[tid * 4 + 0] = (vy0 && vx0) ? wy0 * wx0 : 0.f;
    pidx[tid * 4 + 1] = (y0c * W_ + x1c) << 7;  pw[tid * 4 + 1] = (vy0 && vx1) ? wy0 * wx1 : 0.f;
    pidx[tid * 4 + 2] = (y1c * W_ + x0c) << 7;  pw[tid * 4 + 2] = (vy1 && vx0) ? wy1 * wx0 : 0.f;
    pidx[tid * 4 + 3] = (y1c * W_ + x1c) << 7;  pw[tid * 4 + 3] = (vy1 && vx1) ? wy1 * wx1 : 0.f;
  }
  __syncthreads();

  const unsigned short* xb = xcl + (size_t)b * (H_ * W_ * CIN_);
#pragma unroll
  for (int it = 0; it < 5; it++) {
    int i = it * 256 + tid;            // (pxh, oct), oct fastest
    int oct = i & 15;
    int pxh = i >> 4;                  // 0..79
    int4   I  = *(const int4*)&pidx[pxh * 4];
    float4 Wv = *(const float4*)&pw[pxh * 4];
    short8 c00 = *(const short8*)(xb + I.x + oct * 8);
    short8 c01 = *(const short8*)(xb + I.y + oct * 8);
    short8 c10 = *(const short8*)(xb + I.z + oct * 8);
    short8 c11 = *(const short8*)(xb + I.w + oct * 8);
    short8 r;
#pragma unroll
    for (int i2 = 0; i2 < 8; i2++) {
      float v = Wv.x * bu2f((unsigned short)c00[i2]) +
                Wv.y * bu2f((unsigned short)c01[i2]) +
                Wv.z * bu2f((unsigned short)c10[i2]) +
                Wv.w * bu2f((unsigned short)c11[i2]);
      r[i2] = (short)f2bu(v);
    }
    int p  = b * 1600 + (ho0 + (pxh / 40)) * 40 + (pxh % 40);
    int pt = p >> 4, lm = p & 15;
    int ks = kk * 4 + (oct >> 2);
    int qd = oct & 3;
    *(short8*)&Spk[(((size_t)pt * NKS_ + ks) * 64 + qd * 16 + lm) * 8] = r;
  }
}

// --- K2b: MFMA GEMM, full K, fused channel stats. 64c x 64px, 4 waves,
// 16 KB dbuf LDS + 2 KB stats scratch -> still 8 blocks/CU. Grid 1600,
// XCD-affine (bid&7 == b&7 matches Spk writer). Plain single-C store (no
// split, no atomic RMW on C). Stats: lm-shuffle (16 px/wave) -> LDS cross-
// wave reduce -> 2 atomics per cout per block (400-deep chains, hidden).
__global__ __launch_bounds__(256) void k_gemm(const unsigned short* __restrict__ Apk,
                                              const unsigned short* __restrict__ Spk,
                                              float* __restrict__ outp,
                                              float* __restrict__ accum) {
  __shared__ __align__(16) unsigned short a_sh[2][2048];  // 8 KB
  __shared__ __align__(16) unsigned short b_sh[2][2048];  // 8 KB
  __shared__ float sF1[4][64], sF2[4][64];                // 2 KB

  const int tid = threadIdx.x;
  const int wv = tid >> 6;
  const int ln = tid & 63;
  const int lm = ln & 15;
  const int qd = ln >> 4;

  // XCD-affine decomposition: 1600 = 8 xcd * 2 b_hi * 25 pxg * 4 cq
  const int bid = blockIdx.x;
  const int xcd = bid & 7;
  const int i   = bid >> 3;            // 0..199
  const int b   = xcd + 8 * (i / 100);
  const int r_  = i % 100;
  const int pxg = r_ >> 2;             // 0..24
  const int cq  = r_ & 3;              // cout quarter
  const int pt0 = b * 100 + pxg * 4;
  const int cbase = cq * 64;

  const unsigned short* agbase = Apk + cbase * 32 + tid * 8;             // +ks*8192
  const unsigned short* bgbase = Spk + (size_t)(pt0 + wv) * NKS_ * 512 + ln * 8; // +ks*512

  floatx4 acc[4];
#pragma unroll
  for (int mt = 0; mt < 4; mt++) acc[mt] = (floatx4){0.f, 0.f, 0.f, 0.f};

  gl_lds16(agbase, &a_sh[0][0] + wv * 512);
  gl_lds16(bgbase, &b_sh[0][0] + wv * 512);
  __syncthreads();

  for (int ks = 0; ks < NKS_; ks++) {
    const int buf = ks & 1, nb = buf ^ 1;
    if (ks + 1 < NKS_) {
      gl_lds16(agbase + (size_t)(ks + 1) * 8192, &a_sh[nb][0] + wv * 512);
      gl_lds16(bgbase + (size_t)(ks + 1) * 512,  &b_sh[nb][0] + wv * 512);
    }
    const unsigned short* al = &a_sh[buf][0] + lm * 32 + qd * 8;
    const unsigned short* bl = &b_sh[buf][0] + wv * 512 + ln * 8;
    short8 a0 = *(const short8*)(al + 0 * 512);
    short8 a1 = *(const short8*)(al + 1 * 512);
    short8 a2 = *(const short8*)(al + 2 * 512);
    short8 a3 = *(const short8*)(al + 3 * 512);
    short8 bv = *(const short8*)(bl);
    acc[0] = __builtin_amdgcn_mfma_f32_16x16x32_bf16(a0, bv, acc[0], 0, 0, 0);
    acc[1] = __builtin_amdgcn_mfma_f32_16x16x32_bf16(a1, bv, acc[1], 0, 0, 0);
    acc[2] = __builtin_amdgcn_mfma_f32_16x16x32_bf16(a2, bv, acc[2], 0, 0, 0);
    acc[3] = __builtin_amdgcn_mfma_f32_16x16x32_bf16(a3, bv, acc[3], 0, 0, 0);
    __syncthreads();
  }

  // Epilogue: plain C store + fused stats (C/D layout verified r3-r11).
  const int p = (pt0 + wv) * 16 + lm;          // p = b*1600 + rem by construction
  float* ob = outp + (size_t)b * COUT_ * 1600 + (p - b * 1600);
  float s1[16], s2[16];
#pragma unroll
  for (int mt = 0; mt < 4; mt++) {
#pragma unroll
    for (int r = 0; r < 4; r++) {
      const int c = cbase + mt * 16 + qd * 4 + r;
      float v = acc[mt][r];
      ob[(size_t)c * 1600] = v;
      s1[mt * 4 + r] = v;
      s2[mt * 4 + r] = v * v;
    }
  }
#pragma unroll
  for (int d = 1; d < 16; d <<= 1) {
#pragma unroll
    for (int i2 = 0; i2 < 16; i2++) {
      s1[i2] += __shfl_xor(s1[i2], d, 64);
      s2[i2] += __shfl_xor(s2[i2], d, 64);
    }
  }
  if (lm == 0) {
#pragma unroll
    for (int i2 = 0; i2 < 16; i2++) {
      int cl = (i2 >> 2) * 16 + qd * 4 + (i2 & 3);   // 0..63
      sF1[wv][cl] = s1[i2];
      sF2[wv][cl] = s2[i2];
    }
  }
  __syncthreads();
  if (tid < 64) {
    float a1 = sF1[0][tid] + sF1[1][tid] + sF1[2][tid] + sF1[3][tid];
    float a2 = sF2[0][tid] + sF2[1][tid] + sF2[2][tid] + sF2[3][tid];
    atomicAdd(&accum[cbase + tid], a1);
    atomicAdd(&accum[COUT_ + cbase + tid], a2);
  }
}

// --------------------------------------------------- K3: BN + SiLU, in place
__global__ __launch_bounds__(256) void k_bn(float* __restrict__ io,
                                            const float* __restrict__ accum,
                                            const float* __restrict__ gamma,
                                            const float* __restrict__ beta) {
  const int t = blockIdx.x * 256 + threadIdx.x;
  const int i0 = t * 4;
  const int c = (i0 / (HO_ * WO_)) % COUT_;
  const float mean = accum[c] * (1.f / NPIX_);
  const float var  = accum[COUT_ + c] * (1.f / NPIX_) - mean * mean;
  const float inv  = rsqrtf(var + 1e-5f);
  const float g  = gamma[c] * inv;
  const float be = beta[c] - mean * g;
  float4 r = *(const float4*)(io + i0);
  float v[4] = {r.x, r.y, r.z, r.w};
#pragma unroll
  for (int q = 0; q < 4; q++) {
    float u = v[q] * g + be;
    v[q] = u / (1.f + expf(-u));
  }
  *(float4*)(io + i0) = make_float4(v[0], v[1], v[2], v[3]);
}

// ----------------------------------------------------------------- launcher
extern "C" void kernel_launch(void* const* d_in, const int* in_sizes, int n_in,
                              void* d_out, int out_size, void* d_ws, size_t ws_size,
                              hipStream_t stream) {
  const float* x     = (const float*)d_in[0];
  const float* ow    = (const float*)d_in[1];
  const float* ob    = (const float*)d_in[2];
  const float* dw    = (const float*)d_in[3];
  const float* gamma = (const float*)d_in[5];
  const float* beta  = (const float*)d_in[6];
  float* out = (float*)d_out;

  float* off   = (float*)d_ws;                                 // 460800 f
  float* accum = off + B_ * 18 * HO_ * WO_;                    // 512 f
  unsigned short* Apk = (unsigned short*)(accum + 2 * COUT_);  // 294912 us
  unsigned short* Spk = Apk + (size_t)SK_ * COUT_;             // 29491200 us
  unsigned short* xcl = Spk + (size_t)NPIX_ * SK_;             // 13107200 us

  k_pack<<<SK_, 256, 0, stream>>>(dw, Apk, accum);
  k_cl<<<B_ * H_, 256, 0, stream>>>(x, ow, ob, xcl, off);
  k_sample_cl<<<B_ * KK_ * 20, 256, 0, stream>>>(xcl, off, Spk);
  k_gemm<<<1600, 256, 0, stream>>>(Apk, Spk, out, accum);
  k_bn<<<(NPIX_ * COUT_ / 4 + 255) / 256, 256, 0, stream>>>(
      out, accum, gamma, beta);
}